// Round 10
// baseline (1233.130 us; speedup 1.0000x reference)
//
#include <hip/hip_runtime.h>
#include <cstddef>

#define LL 2048
#define TOK 8192   // B*L = 4*2048
#define DM 1024
#define DI 2048
#define NS 16

typedef _Float16 half_t;
typedef __attribute__((ext_vector_type(8))) _Float16 f16x8;
typedef __attribute__((ext_vector_type(4))) _Float16 f16x4;
typedef __attribute__((ext_vector_type(4))) float f32x4;

// ---------- helpers ----------
__device__ __forceinline__ float softplus_f(float x) {
  return fmaxf(x, 0.f) + log1pf(__expf(-fabsf(x)));
}
__device__ __forceinline__ float silu_f(float x) {
  return x / (1.f + __expf(-x));
}
__device__ __forceinline__ void gload_lds16(const void* g, void* l) {
  __builtin_amdgcn_global_load_lds((const __attribute__((address_space(1))) void*)g,
                                   (__attribute__((address_space(3))) void*)l, 16, 0, 0);
}
// DPP row_shr add: after ctrl 0x111,0x112,0x114,0x118 lane15 of each row16 holds the row sum
#define DPP_ADD(v, ctrl) \
  ((v) + __int_as_float(__builtin_amdgcn_update_dpp(0, __float_as_int(v), (ctrl), 0xf, 0xf, true)))

// ---------- static scratch (float units) ----------
//  xh    @ 0            x fp16
//  wlgh  @ 4,194,304    [W_left;W_right] fp16 [4096][1024]
//  wdf   @ 6,291,456    [W_delta;W_B;W_C;zeros] fp16 [2176][2048]
//  woh   @ 10,485,760   W_out fp16
//  left  @ 11,534,336   fp32 (conv input)        [16.78M fl]
//  dlt32 @ 28,311,552   split-K delta accum fp32 [16.78M fl = 8192x2048]
//  xch   @ 45,088,768   conv output fp16         [8.39M fl]
//  bc32  @ 53,477,376   split-K bc accum fp32    [1.05M fl = 8192x128]
//  dlth  @ 61,865,984   delta fp16
//  gateh @ 78,643,200   gate fp16
//  y     @ 95,420,416   fp32
//  nrmh  @ 112,197,632  LN out fp16
//  bc    @ 120,586,240  packed fp32: [row][2n]=B_n, [2n+1]=C_n
__device__ float g_buf[120881152];

// ---------- fp32 -> fp16 staging ----------
__global__ __launch_bounds__(256) void f2h_k(const float* __restrict__ in,
                                             half_t* __restrict__ out, int n4) {
  const int i = blockIdx.x * 256 + threadIdx.x;
  if (i >= n4) return;
  const float4 v = ((const float4*)in)[i];
  f16x4 o;
  o[0] = (half_t)v.x; o[1] = (half_t)v.y; o[2] = (half_t)v.z; o[3] = (half_t)v.w;
  ((f16x4*)out)[i] = o;
}

// ---------- fp16 zero fill (pad rows of the fused delta/BC weight) ----------
__global__ __launch_bounds__(256) void zh_k(half_t* __restrict__ out, int n4) {
  const int i = blockIdx.x * 256 + threadIdx.x;
  if (i >= n4) return;
  f16x4 o;
  o[0] = (half_t)0.f; o[1] = (half_t)0.f; o[2] = (half_t)0.f; o[3] = (half_t)0.f;
  ((f16x4*)out)[i] = o;
}

// ---------- fp32 zero fill (split-K atomic targets) ----------
__global__ __launch_bounds__(256) void zero_f32(float* __restrict__ p, int n4) {
  const int i = blockIdx.x * 256 + threadIdx.x;
  if (i >= n4) return;
  ((float4*)p)[i] = make_float4(0.f, 0.f, 0.f, 0.f);
}

// ---------- fused left+gate GEMM: W = [W_left;W_right] (4096 x 1024) ----------
// left (cols < DI): fp32 out (conv input).  gate (cols >= DI): silu, fp16 out.
// 2048 blocks = 8/CU -- the only GEMM shape here that self-populates the CU;
// its ~1400 cyc/K-step/slot is the target the split-K kernels aim for.
__global__ __launch_bounds__(256) void gemm_mfma_lg(const half_t* __restrict__ A,
                                                    const half_t* __restrict__ W,
                                                    float* __restrict__ left,
                                                    half_t* __restrict__ gateh) {
  __shared__ half_t lA[4096];
  __shared__ half_t lB[4096];
  const int tid = threadIdx.x;
  const int bm0 = blockIdx.y * 128, bn0 = blockIdx.x * 128;
  const int K = DM;
  const int lane = tid & 63, wave = tid >> 6;
  const int q = lane >> 4, mr = lane & 15;
  const int wm = (wave >> 1) * 64, wn = (wave & 1) * 64;
  const int flat1 = tid + 256;
  const int kc0 = tid >> 7, r0 = tid & 127;
  const int kc1 = flat1 >> 7, r1 = flat1 & 127;

  f32x4 acc[4][4];
#pragma unroll
  for (int i = 0; i < 4; ++i)
#pragma unroll
    for (int j = 0; j < 4; ++j) acc[i][j] = (f32x4){0.f, 0.f, 0.f, 0.f};

  for (int k0 = 0; k0 < K; k0 += 32) {
    gload_lds16(A + (size_t)(bm0 + r0) * K + k0 + kc0 * 8, lA + (size_t)tid * 8);
    gload_lds16(A + (size_t)(bm0 + r1) * K + k0 + kc1 * 8, lA + (size_t)flat1 * 8);
    gload_lds16(W + (size_t)(bn0 + r0) * K + k0 + kc0 * 8, lB + (size_t)tid * 8);
    gload_lds16(W + (size_t)(bn0 + r1) * K + k0 + kc1 * 8, lB + (size_t)flat1 * 8);
    __syncthreads();
    f16x8 af[4], bg[4];
#pragma unroll
    for (int t = 0; t < 4; ++t) {
      af[t] = *(const f16x8*)(lA + ((q << 10) + ((wm + t * 16 + mr) << 3)));
      bg[t] = *(const f16x8*)(lB + ((q << 10) + ((wn + t * 16 + mr) << 3)));
    }
#pragma unroll
    for (int i = 0; i < 4; ++i)
#pragma unroll
      for (int j = 0; j < 4; ++j)
        acc[i][j] = __builtin_amdgcn_mfma_f32_16x16x32_f16(af[i], bg[j], acc[i][j], 0, 0, 0);
    __syncthreads();
  }

  const int is_gate = (bn0 >= DI);
  const int cb = bn0 - (is_gate ? DI : 0);
  if (!is_gate) {
#pragma unroll
    for (int i = 0; i < 4; ++i)
#pragma unroll
      for (int j = 0; j < 4; ++j) {
        const int col = cb + wn + j * 16 + mr;
#pragma unroll
        for (int r = 0; r < 4; ++r) {
          const int row = bm0 + wm + i * 16 + q * 4 + r;
          left[(size_t)row * DI + col] = acc[i][j][r];
        }
      }
  } else {
#pragma unroll
    for (int i = 0; i < 4; ++i)
#pragma unroll
      for (int j = 0; j < 4; ++j) {
        const int col = cb + wn + j * 16 + mr;
#pragma unroll
        for (int r = 0; r < 4; ++r) {
          const int row = bm0 + wm + i * 16 + q * 4 + r;
          gateh[(size_t)row * DI + col] = (half_t)silu_f(acc[i][j][r]);
        }
      }
  }
}

// ---------- delta + B/C GEMM, split-K x2, atomic accumulate ------------------
// R6-proven 256x128 / 8-wave structure, but grid (17, 32, 2) = 1088 blocks
// (4.25/CU vs the grid-starved 2/CU): each z-slice covers K/2 = 32 K-steps.
// Raw sums atomicAdd into zeroed fp32 scratch; bias/softplus/clip move to
// delta_fin (activation is not distributive over the K-split).
__global__ __launch_bounds__(512, 4) void gemm_delta_sk(const half_t* __restrict__ A,
                                                        const half_t* __restrict__ W,
                                                        float* __restrict__ dlt32,
                                                        float* __restrict__ bc32) {
  __shared__ half_t lA[8192];   // [kc4][256][8]  16 KB
  __shared__ half_t lB[4096];   // [kc4][128][8]   8 KB
  const int tid = threadIdx.x;
  const int bm0 = blockIdx.y * 256, bn0 = blockIdx.x * 128;
  const int K = DI;
  const int kz0 = blockIdx.z * (DI / 2);
  const int lane = tid & 63, wave = tid >> 6;
  const int q = lane >> 4, mr = lane & 15;
  const int wm = (wave >> 1) * 64, wn = (wave & 1) * 64;
  // A staging: 1024 chunks, 2 per thread
  const int aflat1 = tid + 512;
  const int akc0 = tid >> 8, ar0 = tid & 255;
  const int akc1 = aflat1 >> 8, ar1 = aflat1 & 255;
  // W staging: 512 chunks, 1 per thread
  const int wkc = tid >> 7, wr = tid & 127;

  f32x4 acc[4][4];
#pragma unroll
  for (int i = 0; i < 4; ++i)
#pragma unroll
    for (int j = 0; j < 4; ++j) acc[i][j] = (f32x4){0.f, 0.f, 0.f, 0.f};

  for (int k0 = kz0; k0 < kz0 + DI / 2; k0 += 32) {
    gload_lds16(A + (size_t)(bm0 + ar0) * K + k0 + akc0 * 8, lA + (size_t)tid * 8);
    gload_lds16(A + (size_t)(bm0 + ar1) * K + k0 + akc1 * 8, lA + (size_t)aflat1 * 8);
    gload_lds16(W + (size_t)(bn0 + wr) * K + k0 + wkc * 8, lB + (size_t)tid * 8);
    __syncthreads();
    f16x8 ah[4], bg[4];
#pragma unroll
    for (int t = 0; t < 4; ++t) {
      const int ao = (q << 11) + ((wm + t * 16 + mr) << 3);   // q*256*8
      const int bo = (q << 10) + ((wn + t * 16 + mr) << 3);   // q*128*8
      ah[t] = *(const f16x8*)(lA + ao);
      bg[t] = *(const f16x8*)(lB + bo);
    }
    __builtin_amdgcn_s_setprio(1);
#pragma unroll
    for (int i = 0; i < 4; ++i)
#pragma unroll
      for (int j = 0; j < 4; ++j)
        acc[i][j] = __builtin_amdgcn_mfma_f32_16x16x32_f16(ah[i], bg[j], acc[i][j], 0, 0, 0);
    __builtin_amdgcn_s_setprio(0);
    __syncthreads();
  }

  if (bn0 < DI) {
#pragma unroll
    for (int i = 0; i < 4; ++i) {
#pragma unroll
      for (int j = 0; j < 4; ++j) {
        const int col = bn0 + wn + j * 16 + mr;
#pragma unroll
        for (int r = 0; r < 4; ++r) {
          const int row = bm0 + wm + i * 16 + q * 4 + r;
          atomicAdd(&dlt32[(size_t)row * DI + col], acc[i][j][r]);
        }
      }
    }
  } else {
#pragma unroll
    for (int i = 0; i < 4; ++i) {
#pragma unroll
      for (int j = 0; j < 4; ++j) {
        const int c = wn + j * 16 + mr;   // 0..127 (>=32 are zero-pad, harmless)
#pragma unroll
        for (int r = 0; r < 4; ++r) {
          const int row = bm0 + wm + i * 16 + q * 4 + r;
          atomicAdd(&bc32[(size_t)row * 128 + c], acc[i][j][r]);
        }
      }
    }
  }
}

// ---------- delta epilogue: bias + softplus + clip -> fp16 -------------------
__global__ __launch_bounds__(256) void delta_fin(const float* __restrict__ dlt32,
                                                 const float* __restrict__ bias,
                                                 half_t* __restrict__ dlth) {
  const int i = blockIdx.x * 256 + threadIdx.x;   // over TOK*DI/4
  const float4 v = ((const float4*)dlt32)[i];
  const int col4 = (i * 4) & (DI - 1);
  const float4 bv = *(const float4*)&bias[col4];
  f16x4 o;
  o[0] = (half_t)fminf(fmaxf(softplus_f(v.x + bv.x), 1e-4f), 10.f);
  o[1] = (half_t)fminf(fmaxf(softplus_f(v.y + bv.y), 1e-4f), 10.f);
  o[2] = (half_t)fminf(fmaxf(softplus_f(v.z + bv.z), 1e-4f), 10.f);
  o[3] = (half_t)fminf(fmaxf(softplus_f(v.w + bv.w), 1e-4f), 10.f);
  ((f16x4*)dlth)[i] = o;
}

// ---------- bc epilogue: reorder accum cols into interleaved [2n]/[2n+1] -----
__global__ __launch_bounds__(256) void bc_fin(const float* __restrict__ bc32,
                                              float* __restrict__ bc) {
  const int i = blockIdx.x * 256 + threadIdx.x;   // over TOK*32
  const int row = i >> 5, c = i & 31;
  const int slot = (c < 16) ? (2 * c) : (2 * (c - 16) + 1);
  bc[(size_t)row * 32 + slot] = bc32[(size_t)row * 128 + c];
}

// ---------- out GEMM: split-K x4, atomic accumulate into d_out ---------------
// 128^2 tile, 256 threads; grid (8, 64, 4) = 2048 blocks = 8/CU (was 512 =
// 2/CU, grid-starved at ~5000 cyc/step-slot).  Each z covers K/4 = 16 steps.
// No activation -> atomicAdd straight into the zeroed output.
__global__ __launch_bounds__(256) void gemm_out_sk(const half_t* __restrict__ A,
                                                   const half_t* __restrict__ W,
                                                   float* __restrict__ C) {
  __shared__ half_t lA[4096];
  __shared__ half_t lB[4096];
  const int tid = threadIdx.x;
  const int bm0 = blockIdx.y * 128, bn0 = blockIdx.x * 128;
  const int K = DI, N = DM;
  const int kz0 = blockIdx.z * (DI / 4);
  const int lane = tid & 63, wave = tid >> 6;
  const int q = lane >> 4, mr = lane & 15;
  const int wm = (wave >> 1) * 64, wn = (wave & 1) * 64;
  const int flat1 = tid + 256;
  const int kc0 = tid >> 7, r0 = tid & 127;
  const int kc1 = flat1 >> 7, r1 = flat1 & 127;

  f32x4 acc[4][4];
#pragma unroll
  for (int i = 0; i < 4; ++i)
#pragma unroll
    for (int j = 0; j < 4; ++j) acc[i][j] = (f32x4){0.f, 0.f, 0.f, 0.f};

  for (int k0 = kz0; k0 < kz0 + DI / 4; k0 += 32) {
    gload_lds16(A + (size_t)(bm0 + r0) * K + k0 + kc0 * 8, lA + (size_t)tid * 8);
    gload_lds16(A + (size_t)(bm0 + r1) * K + k0 + kc1 * 8, lA + (size_t)flat1 * 8);
    gload_lds16(W + (size_t)(bn0 + r0) * K + k0 + kc0 * 8, lB + (size_t)tid * 8);
    gload_lds16(W + (size_t)(bn0 + r1) * K + k0 + kc1 * 8, lB + (size_t)flat1 * 8);
    __syncthreads();
    f16x8 af[4], bg[4];
#pragma unroll
    for (int t = 0; t < 4; ++t) {
      af[t] = *(const f16x8*)(lA + ((q << 10) + ((wm + t * 16 + mr) << 3)));
      bg[t] = *(const f16x8*)(lB + ((q << 10) + ((wn + t * 16 + mr) << 3)));
    }
#pragma unroll
    for (int i = 0; i < 4; ++i)
#pragma unroll
      for (int j = 0; j < 4; ++j)
        acc[i][j] = __builtin_amdgcn_mfma_f32_16x16x32_f16(af[i], bg[j], acc[i][j], 0, 0, 0);
    __syncthreads();
  }

#pragma unroll
  for (int i = 0; i < 4; ++i) {
#pragma unroll
    for (int j = 0; j < 4; ++j) {
      const int col = bn0 + wn + j * 16 + mr;
#pragma unroll
      for (int r = 0; r < 4; ++r) {
        const int row = bm0 + wm + i * 16 + q * 4 + r;
        atomicAdd(&C[(size_t)row * N + col], acc[i][j][r]);
      }
    }
  }
}

// ---------- causal depthwise conv(4) + bias + silu -> fp16 only --------------
__global__ __launch_bounds__(256) void conv_silu_k(const float* __restrict__ left,
                                                   const float* __restrict__ cw,
                                                   const float* __restrict__ cb,
                                                   half_t* __restrict__ xch) {
  const int idx = blockIdx.x * 256 + threadIdx.x;  // over TOK*DI
  const int d = idx & (DI - 1);
  const int bt = idx >> 11;
  const int t = bt & (LL - 1);
  const float4 wv = *(const float4*)(cw + (size_t)d * 4);
  float acc = cb[d];
  const size_t base = (size_t)idx;
  if (t >= 3) {
    acc += left[base - 3 * DI] * wv.x + left[base - 2 * DI] * wv.y +
           left[base - DI] * wv.z + left[base] * wv.w;
  } else {
    acc += left[base] * wv.w;
    if (t >= 1) acc += left[base - DI] * wv.z;
    if (t >= 2) acc += left[base - 2 * DI] * wv.y;
  }
  xch[base] = (half_t)silu_f(acc);
}

// ---------- selective scan: DPP reduce, packed LDS, fp16 inputs --------------
#define ST 32
__global__ __launch_bounds__(256) void scan_k(const half_t* __restrict__ dlth,
                                              const half_t* __restrict__ xch,
                                              const half_t* __restrict__ gateh,
                                              const float* __restrict__ bcp,
                                              const float* __restrict__ A_log,
                                              float* __restrict__ y) {
  __shared__ float dx2[16 * 68];
  __shared__ float bcs[ST * 32];
  __shared__ float ys[ST * 16];
  const int tid = threadIdx.x;
  const int b  = blockIdx.x >> 7;
  const int d0 = (blockIdx.x & 127) << 4;
  const int n  = tid & 15;
  const int ch = tid >> 4;
  const float An = -softplus_f(A_log[n]);

  const int t_a = tid >> 4, c_a = tid & 15;
  const int t_b = t_a + 16;

  float h = 0.f;
  const size_t batch_base = (size_t)b * LL * DI + d0;
  const size_t batch_bc   = (size_t)b * LL * 32;

  size_t rb_cur = batch_base;
  float g0, g1;
  {
    const size_t ra = rb_cur + (size_t)t_a * DI + c_a;
    const size_t rbx = rb_cur + (size_t)t_b * DI + c_a;
    const float d0v = (float)dlth[ra], x0v = (float)xch[ra];
    const float d1v = (float)dlth[rbx], x1v = (float)xch[rbx];
    g0 = (float)gateh[ra]; g1 = (float)gateh[rbx];
    const float2 b0 = *(const float2*)&bcp[batch_bc + (size_t)t_a * 32 + 2 * c_a];
    const float2 b1 = *(const float2*)&bcp[batch_bc + (size_t)t_b * 32 + 2 * c_a];
    *(float2*)&dx2[c_a * 68 + t_a * 2] = make_float2(d0v, x0v);
    *(float2*)&dx2[c_a * 68 + t_b * 2] = make_float2(d1v, x1v);
    *(float2*)&bcs[t_a * 32 + 2 * c_a] = b0;
    *(float2*)&bcs[t_b * 32 + 2 * c_a] = b1;
  }
  __syncthreads();

  for (int it = 0; it < LL / ST; ++it) {
    float nd0, nx0, ng0, nd1, nx1, ng1;
    float2 nb0, nb1;
    const size_t rb_nxt = batch_base + (size_t)(it + 1) * ST * DI;
    if (it + 1 < LL / ST) {
      const size_t ra = rb_nxt + (size_t)t_a * DI + c_a;
      const size_t rbx = rb_nxt + (size_t)t_b * DI + c_a;
      nd0 = (float)dlth[ra]; nx0 = (float)xch[ra]; ng0 = (float)gateh[ra];
      nd1 = (float)dlth[rbx]; nx1 = (float)xch[rbx]; ng1 = (float)gateh[rbx];
      const size_t bcb = batch_bc + (size_t)(it + 1) * ST * 32;
      nb0 = *(const float2*)&bcp[bcb + (size_t)t_a * 32 + 2 * c_a];
      nb1 = *(const float2*)&bcp[bcb + (size_t)t_b * 32 + 2 * c_a];
    }

    const float* dxp = &dx2[ch * 68];
#pragma unroll
    for (int tt = 0; tt < ST; tt += 2) {
      const float4 v = *(const float4*)&dxp[tt * 2];
      const float2 bc0 = *(const float2*)&bcs[tt * 32 + 2 * n];
      const float2 bc1 = *(const float2*)&bcs[(tt + 1) * 32 + 2 * n];
      float ab = __expf(v.x * An);
      h = fmaf(ab, h, v.x * v.y * bc0.x);
      float p = h * bc0.y;
      p = DPP_ADD(p, 0x111); p = DPP_ADD(p, 0x112);
      p = DPP_ADD(p, 0x114); p = DPP_ADD(p, 0x118);
      if (n == 15) ys[tt * 16 + ch] = p;
      ab = __expf(v.z * An);
      h = fmaf(ab, h, v.z * v.w * bc1.x);
      p = h * bc1.y;
      p = DPP_ADD(p, 0x111); p = DPP_ADD(p, 0x112);
      p = DPP_ADD(p, 0x114); p = DPP_ADD(p, 0x118);
      if (n == 15) ys[(tt + 1) * 16 + ch] = p;
    }
    __syncthreads();

    if (it + 1 < LL / ST) {
      *(float2*)&dx2[c_a * 68 + t_a * 2] = make_float2(nd0, nx0);
      *(float2*)&dx2[c_a * 68 + t_b * 2] = make_float2(nd1, nx1);
      *(float2*)&bcs[t_a * 32 + 2 * c_a] = nb0;
      *(float2*)&bcs[t_b * 32 + 2 * c_a] = nb1;
    }
    y[rb_cur + (size_t)t_a * DI + c_a] = ys[t_a * 16 + c_a] * g0;
    y[rb_cur + (size_t)t_b * DI + c_a] = ys[t_b * 16 + c_a] * g1;
    g0 = ng0; g1 = ng1;
    rb_cur = rb_nxt;
    __syncthreads();
  }
}

// ---------- layernorm over d_inner (fp16 out for MFMA consumer) ----------
__global__ __launch_bounds__(256) void ln_k(const float* __restrict__ y,
                                            const float* __restrict__ gam,
                                            const float* __restrict__ bet,
                                            half_t* __restrict__ outn) {
  const int row = blockIdx.x;
  const int tid = threadIdx.x;
  const float* yr = y + (size_t)row * DI;
  const float4 v0 = ((const float4*)yr)[tid];
  const float4 v1 = ((const float4*)yr)[tid + 256];
  float s = v0.x + v0.y + v0.z + v0.w + v1.x + v1.y + v1.z + v1.w;
  float q = v0.x * v0.x + v0.y * v0.y + v0.z * v0.z + v0.w * v0.w +
            v1.x * v1.x + v1.y * v1.y + v1.z * v1.z + v1.w * v1.w;
  for (int off = 32; off > 0; off >>= 1) {
    s += __shfl_down(s, off);
    q += __shfl_down(q, off);
  }
  __shared__ float sred[4], qred[4];
  const int wid = tid >> 6;
  if ((tid & 63) == 0) { sred[wid] = s; qred[wid] = q; }
  __syncthreads();
  s = sred[0] + sred[1] + sred[2] + sred[3];
  q = qred[0] + qred[1] + qred[2] + qred[3];
  const float mu = s * (1.f / DI);
  const float rs = rsqrtf(q * (1.f / DI) - mu * mu + 1e-5f);
  half_t* orow = outn + (size_t)row * DI;
  const int c0 = tid * 4, c1 = (tid + 256) * 4;
  f16x4 o;
  o[0] = (half_t)((v0.x - mu) * rs * gam[c0 + 0] + bet[c0 + 0]);
  o[1] = (half_t)((v0.y - mu) * rs * gam[c0 + 1] + bet[c0 + 1]);
  o[2] = (half_t)((v0.z - mu) * rs * gam[c0 + 2] + bet[c0 + 2]);
  o[3] = (half_t)((v0.w - mu) * rs * gam[c0 + 3] + bet[c0 + 3]);
  ((f16x4*)orow)[tid] = o;
  o[0] = (half_t)((v1.x - mu) * rs * gam[c1 + 0] + bet[c1 + 0]);
  o[1] = (half_t)((v1.y - mu) * rs * gam[c1 + 1] + bet[c1 + 1]);
  o[2] = (half_t)((v1.z - mu) * rs * gam[c1 + 2] + bet[c1 + 2]);
  o[3] = (half_t)((v1.w - mu) * rs * gam[c1 + 3] + bet[c1 + 3]);
  ((f16x4*)orow)[tid + 256] = o;
}

// ---------- host launch ----------
extern "C" void kernel_launch(void* const* d_in, const int* in_sizes, int n_in,
                              void* d_out, int out_size, void* d_ws, size_t ws_size,
                              hipStream_t stream) {
  const float* x       = (const float*)d_in[0];
  const float* W_left  = (const float*)d_in[1];
  const float* conv_w  = (const float*)d_in[2];
  const float* conv_b  = (const float*)d_in[3];
  const float* W_delta = (const float*)d_in[4];
  const float* b_delta = (const float*)d_in[5];
  const float* W_B     = (const float*)d_in[6];
  const float* W_C     = (const float*)d_in[7];
  const float* A_log   = (const float*)d_in[8];
  const float* W_right = (const float*)d_in[9];
  const float* ln_g    = (const float*)d_in[10];
  const float* ln_b    = (const float*)d_in[11];
  const float* W_out   = (const float*)d_in[12];

  float* buf = nullptr;
  hipGetSymbolAddress((void**)&buf, HIP_SYMBOL(g_buf));
  half_t* xh    = (half_t*)(buf + 0);
  half_t* wlgh  = (half_t*)(buf + 4194304);   // [W_left;W_right] 4096x1024 fp16
  half_t* wrh   = (half_t*)(buf + 5242880);
  half_t* wdf   = (half_t*)(buf + 6291456);   // [W_delta;W_B;W_C;zeros] 2176x2048 fp16
  half_t* woh   = (half_t*)(buf + 10485760);
  float* left   = buf + 11534336;
  float* dlt32  = buf + 28311552;             // 8192x2048 fp32 split-K accum
  half_t* xch   = (half_t*)(buf + 45088768);
  float* bc32   = buf + 53477376;             // 8192x128 fp32 split-K accum
  half_t* dlth  = (half_t*)(buf + 61865984);
  half_t* gateh = (half_t*)(buf + 78643200);
  float* yv     = buf + 95420416;
  half_t* nrmh  = (half_t*)(buf + 112197632);
  float* bc     = buf + 120586240;

  // zero the split-K atomic targets (and d_out)
  zero_f32<<<16384, 256, 0, stream>>>(dlt32, TOK * DI / 4);
  zero_f32<<<1024, 256, 0, stream>>>(bc32, TOK * 128 / 4);
  zero_f32<<<8192, 256, 0, stream>>>((float*)d_out, TOK * DM / 4);

  // fp32 -> fp16 staging
  f2h_k<<<8192, 256, 0, stream>>>(x, xh, TOK * DM / 4);
  f2h_k<<<2048, 256, 0, stream>>>(W_left, wlgh, DI * DM / 4);
  f2h_k<<<2048, 256, 0, stream>>>(W_right, wrh, DI * DM / 4);
  f2h_k<<<2048, 256, 0, stream>>>(W_out, woh, DM * DI / 4);
  // fused delta/BC weight: rows 0..2047 = W_delta, 2048..2063 = W_B,
  // 2064..2079 = W_C, 2080..2175 = zeros
  f2h_k<<<4096, 256, 0, stream>>>(W_delta, wdf, DI * DI / 4);
  f2h_k<<<32, 256, 0, stream>>>(W_B, wdf + (size_t)DI * DI, NS * DI / 4);
  f2h_k<<<32, 256, 0, stream>>>(W_C, wdf + (size_t)(DI + NS) * DI, NS * DI / 4);
  zh_k<<<192, 256, 0, stream>>>(wdf + (size_t)(DI + 2 * NS) * DI, 96 * DI / 4);

  // left = x @ W_left^T (fp32) ; gate = silu(x @ W_right^T) (fp16) -- fused
  gemm_mfma_lg<<<dim3(2 * DI / 128, TOK / 128), 256, 0, stream>>>(xh, wlgh, left, gateh);
  // xch = fp16(silu(causal_conv(left)))
  conv_silu_k<<<TOK * DI / 256, 256, 0, stream>>>(left, conv_w, conv_b, xch);
  // raw delta/bc sums, split-K x2 (1088 blocks)
  gemm_delta_sk<<<dim3(17, TOK / 256, 2), 512, 0, stream>>>(xch, wdf, dlt32, bc32);
  // delta = fp16(clip(softplus(sum + bias))); bc reorder
  delta_fin<<<TOK * DI / 1024, 256, 0, stream>>>(dlt32, b_delta, dlth);
  bc_fin<<<TOK * 32 / 256, 256, 0, stream>>>(bc32, bc);
  // selective scan with fused gate (fp16 inputs, fp32 state + output)
  scan_k<<<512, 256, 0, stream>>>(dlth, xch, gateh, bc, A_log, yv);
  // layernorm -> fp16
  ln_k<<<TOK, 256, 0, stream>>>(yv, ln_g, ln_b, nrmh);
  // out = nrm @ W_out^T, split-K x4 atomic into zeroed d_out (2048 blocks)
  gemm_out_sk<<<dim3(DM / 128, TOK / 128, 4), 256, 0, stream>>>(nrmh, woh, (float*)d_out);
}

// Round 11
// 909.394 us; speedup vs baseline: 1.3560x; 1.3560x over previous
//
#include <hip/hip_runtime.h>
#include <cstddef>

#define LL 2048
#define TOK 8192   // B*L = 4*2048
#define DM 1024
#define DI 2048
#define NS 16

typedef _Float16 half_t;
typedef __attribute__((ext_vector_type(8))) _Float16 f16x8;
typedef __attribute__((ext_vector_type(4))) _Float16 f16x4;
typedef __attribute__((ext_vector_type(4))) float f32x4;

// ---------- helpers ----------
__device__ __forceinline__ float softplus_f(float x) {
  return fmaxf(x, 0.f) + log1pf(__expf(-fabsf(x)));
}
__device__ __forceinline__ float silu_f(float x) {
  return x / (1.f + __expf(-x));
}
__device__ __forceinline__ void gload_lds16(const void* g, void* l) {
  __builtin_amdgcn_global_load_lds((const __attribute__((address_space(1))) void*)g,
                                   (__attribute__((address_space(3))) void*)l, 16, 0, 0);
}
// DPP row_shr add: after ctrl 0x111,0x112,0x114,0x118 lane15 of each row16 holds the row sum
#define DPP_ADD(v, ctrl) \
  ((v) + __int_as_float(__builtin_amdgcn_update_dpp(0, __float_as_int(v), (ctrl), 0xf, 0xf, true)))

// ---------- static scratch (float units) ----------
//  xh    @ 0            x fp16
//  wlgh  @ 4,194,304    [W_left;W_right] fp16 [4096][1024]
//  wdf   @ 6,291,456    [W_delta;W_B;W_C;zeros] fp16 [2176][2048]
//  woh   @ 10,485,760   W_out fp16
//  left  @ 11,534,336
//  xc    @ 28,311,552
//  xch   @ 45,088,768   xc fp16
//  dlt   @ 61,865,984
//  gate  @ 78,643,200
//  y     @ 95,420,416
//  nrmh  @ 112,197,632  LN out fp16
//  bc    @ 120,586,240  packed: [row][2n]=B_n, [2n+1]=C_n
__device__ float g_buf[120881152];

// ---------- fp32 -> fp16 staging ----------
__global__ __launch_bounds__(256) void f2h_k(const float* __restrict__ in,
                                             half_t* __restrict__ out, int n4) {
  const int i = blockIdx.x * 256 + threadIdx.x;
  if (i >= n4) return;
  const float4 v = ((const float4*)in)[i];
  f16x4 o;
  o[0] = (half_t)v.x; o[1] = (half_t)v.y; o[2] = (half_t)v.z; o[3] = (half_t)v.w;
  ((f16x4*)out)[i] = o;
}

// ---------- fp16 zero fill (pad rows of the fused delta/BC weight) ----------
__global__ __launch_bounds__(256) void zh_k(half_t* __restrict__ out, int n4) {
  const int i = blockIdx.x * 256 + threadIdx.x;
  if (i >= n4) return;
  f16x4 o;
  o[0] = (half_t)0.f; o[1] = (half_t)0.f; o[2] = (half_t)0.f; o[3] = (half_t)0.f;
  ((f16x4*)out)[i] = o;
}

// ---------- fp16 MFMA GEMM: C[M,N] = act(A[M,K] @ W[N,K]^T + bias), fp32 out --
template <int ACT>   // 0 none, 1 silu
__global__ __launch_bounds__(256) void gemm_mfma(const half_t* __restrict__ A,
                                                 const half_t* __restrict__ W,
                                                 const float* __restrict__ bias,
                                                 float* __restrict__ C,
                                                 int M, int N, int K) {
  __shared__ half_t lA[4096];   // 8 KB
  __shared__ half_t lB[4096];   // 8 KB
  const int tid = threadIdx.x;
  const int bm0 = blockIdx.y * 128, bn0 = blockIdx.x * 128;
  const int lane = tid & 63, wave = tid >> 6;
  const int q = lane >> 4, mr = lane & 15;
  const int wm = (wave >> 1) * 64, wn = (wave & 1) * 64;
  const int flat0 = tid, flat1 = tid + 256;
  const int kc0 = flat0 >> 7, r0 = flat0 & 127;
  const int kc1 = flat1 >> 7, r1 = flat1 & 127;

  f32x4 acc[4][4];
#pragma unroll
  for (int i = 0; i < 4; ++i)
#pragma unroll
    for (int j = 0; j < 4; ++j) acc[i][j] = (f32x4){0.f, 0.f, 0.f, 0.f};

  for (int k0 = 0; k0 < K; k0 += 32) {
    gload_lds16(A + (size_t)(bm0 + r0) * K + k0 + kc0 * 8, lA + (size_t)flat0 * 8);
    gload_lds16(A + (size_t)(bm0 + r1) * K + k0 + kc1 * 8, lA + (size_t)flat1 * 8);
    gload_lds16(W + (size_t)(bn0 + r0) * K + k0 + kc0 * 8, lB + (size_t)flat0 * 8);
    gload_lds16(W + (size_t)(bn0 + r1) * K + k0 + kc1 * 8, lB + (size_t)flat1 * 8);
    __syncthreads();
    f16x8 af[4], bg[4];
#pragma unroll
    for (int t = 0; t < 4; ++t) {
      af[t] = *(const f16x8*)(lA + ((q << 10) + ((wm + t * 16 + mr) << 3)));
      bg[t] = *(const f16x8*)(lB + ((q << 10) + ((wn + t * 16 + mr) << 3)));
    }
#pragma unroll
    for (int i = 0; i < 4; ++i)
#pragma unroll
      for (int j = 0; j < 4; ++j)
        acc[i][j] = __builtin_amdgcn_mfma_f32_16x16x32_f16(af[i], bg[j], acc[i][j], 0, 0, 0);
    __syncthreads();
  }

#pragma unroll
  for (int i = 0; i < 4; ++i) {
#pragma unroll
    for (int j = 0; j < 4; ++j) {
      const int col = bn0 + wn + j * 16 + mr;
      const float bv = bias ? bias[col] : 0.f;
#pragma unroll
      for (int r = 0; r < 4; ++r) {
        const int row = bm0 + wm + i * 16 + q * 4 + r;
        float v = acc[i][j][r] + bv;
        if (ACT == 1) v = silu_f(v);
        C[(size_t)row * N + col] = v;
      }
    }
  }
}

// ---------- fused left+gate GEMM: W = [W_left;W_right] (4096 x 1024) ----------
__global__ __launch_bounds__(256) void gemm_mfma_lg(const half_t* __restrict__ A,
                                                    const half_t* __restrict__ W,
                                                    float* __restrict__ left,
                                                    float* __restrict__ gate) {
  __shared__ half_t lA[4096];
  __shared__ half_t lB[4096];
  const int tid = threadIdx.x;
  const int bm0 = blockIdx.y * 128, bn0 = blockIdx.x * 128;
  const int K = DM;
  const int lane = tid & 63, wave = tid >> 6;
  const int q = lane >> 4, mr = lane & 15;
  const int wm = (wave >> 1) * 64, wn = (wave & 1) * 64;
  const int flat1 = tid + 256;
  const int kc0 = tid >> 7, r0 = tid & 127;
  const int kc1 = flat1 >> 7, r1 = flat1 & 127;

  f32x4 acc[4][4];
#pragma unroll
  for (int i = 0; i < 4; ++i)
#pragma unroll
    for (int j = 0; j < 4; ++j) acc[i][j] = (f32x4){0.f, 0.f, 0.f, 0.f};

  for (int k0 = 0; k0 < K; k0 += 32) {
    gload_lds16(A + (size_t)(bm0 + r0) * K + k0 + kc0 * 8, lA + (size_t)tid * 8);
    gload_lds16(A + (size_t)(bm0 + r1) * K + k0 + kc1 * 8, lA + (size_t)flat1 * 8);
    gload_lds16(W + (size_t)(bn0 + r0) * K + k0 + kc0 * 8, lB + (size_t)tid * 8);
    gload_lds16(W + (size_t)(bn0 + r1) * K + k0 + kc1 * 8, lB + (size_t)flat1 * 8);
    __syncthreads();
    f16x8 af[4], bg[4];
#pragma unroll
    for (int t = 0; t < 4; ++t) {
      af[t] = *(const f16x8*)(lA + ((q << 10) + ((wm + t * 16 + mr) << 3)));
      bg[t] = *(const f16x8*)(lB + ((q << 10) + ((wn + t * 16 + mr) << 3)));
    }
#pragma unroll
    for (int i = 0; i < 4; ++i)
#pragma unroll
      for (int j = 0; j < 4; ++j)
        acc[i][j] = __builtin_amdgcn_mfma_f32_16x16x32_f16(af[i], bg[j], acc[i][j], 0, 0, 0);
    __syncthreads();
  }

  const int is_gate = (bn0 >= DI);
  float* out = is_gate ? gate : left;
  const int cb = bn0 - (is_gate ? DI : 0);
#pragma unroll
  for (int i = 0; i < 4; ++i) {
#pragma unroll
    for (int j = 0; j < 4; ++j) {
      const int col = cb + wn + j * 16 + mr;
#pragma unroll
      for (int r = 0; r < 4; ++r) {
        const int row = bm0 + wm + i * 16 + q * 4 + r;
        float v = acc[i][j][r];
        if (is_gate) v = silu_f(v);
        out[(size_t)row * DI + col] = v;
      }
    }
  }
}

// ---------- fused delta + B/C GEMM, 256x128 tile, 512 threads (8 waves) ------
// Session-best configuration (R6: e2e 909 us, delta_bc 286 us).  Single-term
// fp16 (Wl correction dropped -- measured zero absmax impact).  W = [W_delta;
// W_B; W_C; zero-pad] as [2176][2048]; grid x = 17 col-blocks.  bn0 < 2048 ->
// delta = clip(softplus(acc+bias)); bn0 == 2048 -> interleaved bc write
// (replaces the separate bc_mfma dispatch).  2 blocks/CU co-resident.
// NOTE (session ledger): 1-phase/dbuf/counted-vmcnt/8-phase/BK=64/256^2/
// split-K-atomic all measured within [269,363] us on this shape -- the
// 2-barrier 256x128 form here is the empirical optimum.
__global__ __launch_bounds__(512, 4) void gemm_delta_bc(const half_t* __restrict__ A,
                                                        const half_t* __restrict__ W,
                                                        const float* __restrict__ bias,
                                                        float* __restrict__ dlt,
                                                        float* __restrict__ bcout) {
  __shared__ half_t lA[8192];   // [kc4][256][8]  16 KB
  __shared__ half_t lB[4096];   // [kc4][128][8]   8 KB
  const int tid = threadIdx.x;
  const int bm0 = blockIdx.y * 256, bn0 = blockIdx.x * 128;
  const int K = DI;
  const int lane = tid & 63, wave = tid >> 6;
  const int q = lane >> 4, mr = lane & 15;
  const int wm = (wave >> 1) * 64, wn = (wave & 1) * 64;
  // A staging: 1024 chunks, 2 per thread
  const int aflat1 = tid + 512;
  const int akc0 = tid >> 8, ar0 = tid & 255;
  const int akc1 = aflat1 >> 8, ar1 = aflat1 & 255;
  // W staging: 512 chunks, 1 per thread
  const int wkc = tid >> 7, wr = tid & 127;

  f32x4 acc[4][4];
#pragma unroll
  for (int i = 0; i < 4; ++i)
#pragma unroll
    for (int j = 0; j < 4; ++j) acc[i][j] = (f32x4){0.f, 0.f, 0.f, 0.f};

  for (int k0 = 0; k0 < K; k0 += 32) {
    gload_lds16(A + (size_t)(bm0 + ar0) * K + k0 + akc0 * 8, lA + (size_t)tid * 8);
    gload_lds16(A + (size_t)(bm0 + ar1) * K + k0 + akc1 * 8, lA + (size_t)aflat1 * 8);
    gload_lds16(W + (size_t)(bn0 + wr) * K + k0 + wkc * 8, lB + (size_t)tid * 8);
    __syncthreads();
    f16x8 ah[4], bg[4];
#pragma unroll
    for (int t = 0; t < 4; ++t) {
      const int ao = (q << 11) + ((wm + t * 16 + mr) << 3);   // q*256*8
      const int bo = (q << 10) + ((wn + t * 16 + mr) << 3);   // q*128*8
      ah[t] = *(const f16x8*)(lA + ao);
      bg[t] = *(const f16x8*)(lB + bo);
    }
    __builtin_amdgcn_s_setprio(1);
#pragma unroll
    for (int i = 0; i < 4; ++i)
#pragma unroll
      for (int j = 0; j < 4; ++j)
        acc[i][j] = __builtin_amdgcn_mfma_f32_16x16x32_f16(ah[i], bg[j], acc[i][j], 0, 0, 0);
    __builtin_amdgcn_s_setprio(0);
    __syncthreads();
  }

  if (bn0 < DI) {
    // delta path: clip(softplus(acc + bias))
#pragma unroll
    for (int i = 0; i < 4; ++i) {
#pragma unroll
      for (int j = 0; j < 4; ++j) {
        const int col = bn0 + wn + j * 16 + mr;
        const float bv = bias[col];
#pragma unroll
        for (int r = 0; r < 4; ++r) {
          const int row = bm0 + wm + i * 16 + q * 4 + r;
          float v = softplus_f(acc[i][j][r] + bv);
          v = fminf(fmaxf(v, 1e-4f), 10.f);
          dlt[(size_t)row * DI + col] = v;
        }
      }
    }
  } else {
    // B/C path: local col c in [0,32): c<16 -> B_c at slot 2c, else C_(c-16)
    // at slot 2(c-16)+1.  Cols >= 32 hit the zero-pad rows; skip.
#pragma unroll
    for (int i = 0; i < 4; ++i) {
#pragma unroll
      for (int j = 0; j < 4; ++j) {
        const int c = wn + j * 16 + mr;
        if (c < 32) {
          const int slot = (c < 16) ? (2 * c) : (2 * (c - 16) + 1);
#pragma unroll
          for (int r = 0; r < 4; ++r) {
            const int row = bm0 + wm + i * 16 + q * 4 + r;
            bcout[(size_t)row * 32 + slot] = acc[i][j][r];
          }
        }
      }
    }
  }
}

// ---------- causal depthwise conv(4) + bias + silu (fp32 + fp16 out) ----------
__global__ __launch_bounds__(256) void conv_silu_k(const float* __restrict__ left,
                                                   const float* __restrict__ cw,
                                                   const float* __restrict__ cb,
                                                   float* __restrict__ xc,
                                                   half_t* __restrict__ xch) {
  const int idx = blockIdx.x * 256 + threadIdx.x;  // over TOK*DI
  const int d = idx & (DI - 1);
  const int bt = idx >> 11;
  const int t = bt & (LL - 1);
  const float4 wv = *(const float4*)(cw + (size_t)d * 4);
  float acc = cb[d];
  const size_t base = (size_t)idx;
  if (t >= 3) {
    acc += left[base - 3 * DI] * wv.x + left[base - 2 * DI] * wv.y +
           left[base - DI] * wv.z + left[base] * wv.w;
  } else {
    acc += left[base] * wv.w;
    if (t >= 1) acc += left[base - DI] * wv.z;
    if (t >= 2) acc += left[base - 2 * DI] * wv.y;
  }
  const float v = silu_f(acc);
  xc[base] = v;
  xch[base] = (half_t)v;
}

// ---------- selective scan: DPP reduce, packed LDS, prefetch pipeline ----------
#define ST 32
__global__ __launch_bounds__(256) void scan_k(const float* __restrict__ delta,
                                              const float* __restrict__ xc,
                                              const float* __restrict__ gate,
                                              const float* __restrict__ bcp,
                                              const float* __restrict__ A_log,
                                              float* __restrict__ y) {
  __shared__ float dx2[16 * 68];
  __shared__ float bcs[ST * 32];
  __shared__ float ys[ST * 16];
  const int tid = threadIdx.x;
  const int b  = blockIdx.x >> 7;
  const int d0 = (blockIdx.x & 127) << 4;
  const int n  = tid & 15;
  const int ch = tid >> 4;
  const float An = -softplus_f(A_log[n]);

  const int t_a = tid >> 4, c_a = tid & 15;
  const int t_b = t_a + 16;

  float h = 0.f;
  const size_t batch_base = (size_t)b * LL * DI + d0;
  const size_t batch_bc   = (size_t)b * LL * 32;

  size_t rb_cur = batch_base;
  float g0, g1;
  {
    const size_t ra = rb_cur + (size_t)t_a * DI + c_a;
    const size_t rbx = rb_cur + (size_t)t_b * DI + c_a;
    const float d0v = delta[ra], x0v = xc[ra];
    const float d1v = delta[rbx], x1v = xc[rbx];
    g0 = gate[ra]; g1 = gate[rbx];
    const float2 b0 = *(const float2*)&bcp[batch_bc + (size_t)t_a * 32 + 2 * c_a];
    const float2 b1 = *(const float2*)&bcp[batch_bc + (size_t)t_b * 32 + 2 * c_a];
    *(float2*)&dx2[c_a * 68 + t_a * 2] = make_float2(d0v, x0v);
    *(float2*)&dx2[c_a * 68 + t_b * 2] = make_float2(d1v, x1v);
    *(float2*)&bcs[t_a * 32 + 2 * c_a] = b0;
    *(float2*)&bcs[t_b * 32 + 2 * c_a] = b1;
  }
  __syncthreads();

  for (int it = 0; it < LL / ST; ++it) {
    float nd0, nx0, ng0, nd1, nx1, ng1;
    float2 nb0, nb1;
    const size_t rb_nxt = batch_base + (size_t)(it + 1) * ST * DI;
    if (it + 1 < LL / ST) {
      const size_t ra = rb_nxt + (size_t)t_a * DI + c_a;
      const size_t rbx = rb_nxt + (size_t)t_b * DI + c_a;
      nd0 = delta[ra]; nx0 = xc[ra]; ng0 = gate[ra];
      nd1 = delta[rbx]; nx1 = xc[rbx]; ng1 = gate[rbx];
      const size_t bcb = batch_bc + (size_t)(it + 1) * ST * 32;
      nb0 = *(const float2*)&bcp[bcb + (size_t)t_a * 32 + 2 * c_a];
      nb1 = *(const float2*)&bcp[bcb + (size_t)t_b * 32 + 2 * c_a];
    }

    const float* dxp = &dx2[ch * 68];
#pragma unroll
    for (int tt = 0; tt < ST; tt += 2) {
      const float4 v = *(const float4*)&dxp[tt * 2];
      const float2 bc0 = *(const float2*)&bcs[tt * 32 + 2 * n];
      const float2 bc1 = *(const float2*)&bcs[(tt + 1) * 32 + 2 * n];
      float ab = __expf(v.x * An);
      h = fmaf(ab, h, v.x * v.y * bc0.x);
      float p = h * bc0.y;
      p = DPP_ADD(p, 0x111); p = DPP_ADD(p, 0x112);
      p = DPP_ADD(p, 0x114); p = DPP_ADD(p, 0x118);
      if (n == 15) ys[tt * 16 + ch] = p;
      ab = __expf(v.z * An);
      h = fmaf(ab, h, v.z * v.w * bc1.x);
      p = h * bc1.y;
      p = DPP_ADD(p, 0x111); p = DPP_ADD(p, 0x112);
      p = DPP_ADD(p, 0x114); p = DPP_ADD(p, 0x118);
      if (n == 15) ys[(tt + 1) * 16 + ch] = p;
    }
    __syncthreads();

    if (it + 1 < LL / ST) {
      *(float2*)&dx2[c_a * 68 + t_a * 2] = make_float2(nd0, nx0);
      *(float2*)&dx2[c_a * 68 + t_b * 2] = make_float2(nd1, nx1);
      *(float2*)&bcs[t_a * 32 + 2 * c_a] = nb0;
      *(float2*)&bcs[t_b * 32 + 2 * c_a] = nb1;
    }
    y[rb_cur + (size_t)t_a * DI + c_a] = ys[t_a * 16 + c_a] * g0;
    y[rb_cur + (size_t)t_b * DI + c_a] = ys[t_b * 16 + c_a] * g1;
    g0 = ng0; g1 = ng1;
    rb_cur = rb_nxt;
    __syncthreads();
  }
}

// ---------- layernorm over d_inner (fp16 out for MFMA consumer) ----------
__global__ __launch_bounds__(256) void ln_k(const float* __restrict__ y,
                                            const float* __restrict__ gam,
                                            const float* __restrict__ bet,
                                            half_t* __restrict__ outn) {
  const int row = blockIdx.x;
  const int tid = threadIdx.x;
  const float* yr = y + (size_t)row * DI;
  const float4 v0 = ((const float4*)yr)[tid];
  const float4 v1 = ((const float4*)yr)[tid + 256];
  float s = v0.x + v0.y + v0.z + v0.w + v1.x + v1.y + v1.z + v1.w;
  float q = v0.x * v0.x + v0.y * v0.y + v0.z * v0.z + v0.w * v0.w +
            v1.x * v1.x + v1.y * v1.y + v1.z * v1.z + v1.w * v1.w;
  for (int off = 32; off > 0; off >>= 1) {
    s += __shfl_down(s, off);
    q += __shfl_down(q, off);
  }
  __shared__ float sred[4], qred[4];
  const int wid = tid >> 6;
  if ((tid & 63) == 0) { sred[wid] = s; qred[wid] = q; }
  __syncthreads();
  s = sred[0] + sred[1] + sred[2] + sred[3];
  q = qred[0] + qred[1] + qred[2] + qred[3];
  const float mu = s * (1.f / DI);
  const float rs = rsqrtf(q * (1.f / DI) - mu * mu + 1e-5f);
  half_t* orow = outn + (size_t)row * DI;
  const int c0 = tid * 4, c1 = (tid + 256) * 4;
  f16x4 o;
  o[0] = (half_t)((v0.x - mu) * rs * gam[c0 + 0] + bet[c0 + 0]);
  o[1] = (half_t)((v0.y - mu) * rs * gam[c0 + 1] + bet[c0 + 1]);
  o[2] = (half_t)((v0.z - mu) * rs * gam[c0 + 2] + bet[c0 + 2]);
  o[3] = (half_t)((v0.w - mu) * rs * gam[c0 + 3] + bet[c0 + 3]);
  ((f16x4*)orow)[tid] = o;
  o[0] = (half_t)((v1.x - mu) * rs * gam[c1 + 0] + bet[c1 + 0]);
  o[1] = (half_t)((v1.y - mu) * rs * gam[c1 + 1] + bet[c1 + 1]);
  o[2] = (half_t)((v1.z - mu) * rs * gam[c1 + 2] + bet[c1 + 2]);
  o[3] = (half_t)((v1.w - mu) * rs * gam[c1 + 3] + bet[c1 + 3]);
  ((f16x4*)orow)[tid + 256] = o;
}

// ---------- host launch ----------
extern "C" void kernel_launch(void* const* d_in, const int* in_sizes, int n_in,
                              void* d_out, int out_size, void* d_ws, size_t ws_size,
                              hipStream_t stream) {
  const float* x       = (const float*)d_in[0];
  const float* W_left  = (const float*)d_in[1];
  const float* conv_w  = (const float*)d_in[2];
  const float* conv_b  = (const float*)d_in[3];
  const float* W_delta = (const float*)d_in[4];
  const float* b_delta = (const float*)d_in[5];
  const float* W_B     = (const float*)d_in[6];
  const float* W_C     = (const float*)d_in[7];
  const float* A_log   = (const float*)d_in[8];
  const float* W_right = (const float*)d_in[9];
  const float* ln_g    = (const float*)d_in[10];
  const float* ln_b    = (const float*)d_in[11];
  const float* W_out   = (const float*)d_in[12];

  float* buf = nullptr;
  hipGetSymbolAddress((void**)&buf, HIP_SYMBOL(g_buf));
  half_t* xh   = (half_t*)(buf + 0);
  half_t* wlgh = (half_t*)(buf + 4194304);   // [W_left;W_right] 4096x1024 fp16
  half_t* wrh  = (half_t*)(buf + 5242880);
  half_t* wdf  = (half_t*)(buf + 6291456);   // [W_delta;W_B;W_C;zeros] 2176x2048 fp16
  half_t* woh  = (half_t*)(buf + 10485760);
  float* left  = buf + 11534336;
  float* xc    = buf + 28311552;
  half_t* xch  = (half_t*)(buf + 45088768);
  float* dlt   = buf + 61865984;
  float* gate  = buf + 78643200;
  float* yv    = buf + 95420416;
  half_t* nrmh = (half_t*)(buf + 112197632);
  float* bc    = buf + 120586240;

  // fp32 -> fp16 staging
  f2h_k<<<8192, 256, 0, stream>>>(x, xh, TOK * DM / 4);
  f2h_k<<<2048, 256, 0, stream>>>(W_left, wlgh, DI * DM / 4);
  f2h_k<<<2048, 256, 0, stream>>>(W_right, wrh, DI * DM / 4);
  f2h_k<<<2048, 256, 0, stream>>>(W_out, woh, DM * DI / 4);
  // fused delta/BC weight: rows 0..2047 = W_delta, 2048..2063 = W_B,
  // 2064..2079 = W_C, 2080..2175 = zeros
  f2h_k<<<4096, 256, 0, stream>>>(W_delta, wdf, DI * DI / 4);
  f2h_k<<<32, 256, 0, stream>>>(W_B, wdf + (size_t)DI * DI, NS * DI / 4);
  f2h_k<<<32, 256, 0, stream>>>(W_C, wdf + (size_t)(DI + NS) * DI, NS * DI / 4);
  zh_k<<<192, 256, 0, stream>>>(wdf + (size_t)(DI + 2 * NS) * DI, 96 * DI / 4);

  // left = x @ W_left^T ; gate = silu(x @ W_right^T)  -- fused, N=4096
  gemm_mfma_lg<<<dim3(2 * DI / 128, TOK / 128), 256, 0, stream>>>(xh, wlgh, left, gate);
  // xc = silu(causal_conv(left))  (fp32 + fp16)
  conv_silu_k<<<TOK * DI / 256, 256, 0, stream>>>(left, conv_w, conv_b, xc, xch);
  // delta = clip(softplus(xc @ W_delta^T + b)) and bc = xc @ [W_B;W_C]^T, fused
  gemm_delta_bc<<<dim3(17, TOK / 256), 512, 0, stream>>>(xch, wdf, b_delta, dlt, bc);
  // selective scan with fused gate (DPP reduce + prefetch pipeline)
  scan_k<<<512, 256, 0, stream>>>(dlt, xc, gate, bc, A_log, yv);
  // layernorm -> fp16
  ln_k<<<TOK, 256, 0, stream>>>(yv, ln_g, ln_b, nrmh);
  // out = nrm @ W_out^T  (fp32 store to d_out)
  gemm_mfma<0><<<dim3(DM / 128, TOK / 128), 256, 0, stream>>>(nrmh, woh, nullptr, (float*)d_out, TOK, DM, DI);
}